// Round 4
// baseline (85.290 us; speedup 1.0000x reference)
//
#include <hip/hip_runtime.h>
#include <hip/hip_bf16.h>

#define NB 128          // tracklets (b)
#define NS 32           // frames per tracklet (s)
#define DF 256          // feature dim
#define NROW (NB*NS)    // 4096
#define KSTEPS (DF/16)  // 16 MFMA k-steps of 16
#define MARGIN 0.3f
#define PANEL (KSTEPS*64)   // bf16x8 slots per tracklet panel

typedef short bf16x8 __attribute__((ext_vector_type(8)));
typedef short bf16x4 __attribute__((ext_vector_type(4)));
typedef float f32x16 __attribute__((ext_vector_type(16)));

__device__ __forceinline__ short f2bf(float x) {      // RTNE float->bf16 bits
    unsigned u = __float_as_uint(x);
    u += 0x7fffu + ((u >> 16) & 1u);
    return (short)(u >> 16);
}

// ---------------- Kernel 1: normalize -> hi-bf16 fragment tiles + init ap/an ----------------
// Tile layout (per tracklet): slot = (trk*KSTEPS + ks)*64 + lane, 8 bf16 per slot.
// lane l covers frame (l&31), k = ks*16 + (l>>5)*8 + e  (same mapping for A and B; Gram-symmetric).
__global__ __launch_bounds__(64) void norm_kernel(const float* __restrict__ in,
                                                  short* __restrict__ Xhi,
                                                  unsigned* __restrict__ apbuf,
                                                  unsigned* __restrict__ anbuf) {
    const int row = blockIdx.x;      // 0..4095
    const int lane = threadIdx.x;    // one float4 each
    const float4 v = ((const float4*)(in + (size_t)row * DF))[lane];
    float s = v.x*v.x + v.y*v.y + v.z*v.z + v.w*v.w;
    #pragma unroll
    for (int off = 32; off; off >>= 1) s += __shfl_xor(s, off);
    const float inv = 1.0f / fmaxf(sqrtf(s), 1e-12f);
    const float o[4] = {v.x*inv, v.y*inv, v.z*inv, v.w*inv};

    const int trk = row >> 5, r32 = row & 31;
    const int k4 = lane * 4;
    const int ks = k4 >> 4;
    const int kq = k4 & 15;
    const int tl = ((kq >> 3) << 5) | r32;
    const size_t off8 = ((size_t)(trk * KSTEPS + ks) * 64 + tl) * 8 + (kq & 7);

    bf16x4 hv;
    #pragma unroll
    for (int c = 0; c < 4; c++) hv[c] = f2bf(o[c]);
    *(bf16x4*)(Xhi + off8) = hv;

    if (row < NB && lane == 0) {           // init anchor accumulators (runs before pair_kernel)
        apbuf[row] = 0u;                   // max over nonneg d
        anbuf[row] = 0x7F800000u;          // +inf
    }
}

// ---------------- Kernel 2: 1x2 pair-tiles per wave, MFMA + acc-domain epilogue ----------------
// 8192 waves (2048 blocks); 4 waves/block share the A panel (same i) via L1.
__global__ __launch_bounds__(256) void pair_kernel(const short* __restrict__ Xhi,
                                                   const int* __restrict__ tgt,
                                                   unsigned* __restrict__ apbuf,
                                                   unsigned* __restrict__ anbuf) {
    const int w = threadIdx.x >> 6;
    const int l = threadIdx.x & 63;
    const int h = l >> 5;
    const int t32 = l & 31;
    const int wj = blockIdx.x * 4 + w;   // 0..63
    const int i  = blockIdx.y;           // 0..127
    const int j0 = wj * 2;

    const bf16x8* P  = (const bf16x8*)Xhi;
    const bf16x8* A  = P + (size_t)i  * PANEL + l;
    const bf16x8* B0 = P + (size_t)j0 * PANEL + l;
    const bf16x8* B1 = B0 + PANEL;

    f32x16 acc0, acc1;
    #pragma unroll
    for (int r = 0; r < 16; r++) { acc0[r] = 0.0f; acc1[r] = 0.0f; }

    #pragma unroll
    for (int ks = 0; ks < KSTEPS; ks++) {
        const bf16x8 a  = A[ks * 64];
        const bf16x8 b0 = B0[ks * 64];
        const bf16x8 b1 = B1[ks * 64];
        acc0 = __builtin_amdgcn_mfma_f32_32x32x16_bf16(a, b0, acc0, 0, 0, 0);
        acc1 = __builtin_amdgcn_mfma_f32_32x32x16_bf16(a, b1, acc1, 0, 0, 0);
    }

    const int ti = tgt[i];

    __shared__ float buf[4][64];
    __shared__ float kv[4][2];

    // Acc-domain epilogue: d = sqrt(clip(2-2a)) monotone decreasing =>
    // colmin(d)<->colmax(a), rowmin(d)<->rowmax(a), K-th largest d <-> K-th smallest a,
    // pos-combine max(d)<->min(a), neg-combine min(d)<->max(a).
    auto do_pair = [&](const f32x16& acc, int jj) {
        const bool pos = (ti == tgt[jj]);
        const int K = pos ? 3 : 6;

        // colmax over the 16 in-lane rows + cross-half swap -> amax_col[t], t=l&31
        float cm = acc[0];
        #pragma unroll
        for (int r = 1; r < 16; r++) cm = fmaxf(cm, acc[r]);
        cm = fmaxf(cm, __shfl_xor(cm, 32));

        // rowmax via 5-step butterfly within each 32-lane half (rows live across lanes)
        float rm[16];
        #pragma unroll
        for (int r = 0; r < 16; r++) rm[r] = acc[r];
        #pragma unroll
        for (int s = 1; s <= 16; s <<= 1) {
            #pragma unroll
            for (int r = 0; r < 16; r++) rm[r] = fmaxf(rm[r], __shfl_xor(rm[r], s));
        }

        // candidate sets in LDS: [0..31] colmax by t, [32..63] rowmax by row
        if (l < 32) buf[w][l] = cm;
        if (t32 == 0) {
            #pragma unroll
            for (int r = 0; r < 16; r++) buf[w][32 + ((r & 3) + 8 * (r >> 2) + 4 * h)] = rm[r];
        }

        const float x = buf[w][l];
        const float* cb = &buf[w][h * 32];
        int c = 0, e = 0;
        #pragma unroll
        for (int q = 0; q < 8; q++) {
            const float4 y = *(const float4*)(cb + 4 * q);
            c += (y.x < x) + (y.y < x) + (y.z < x) + (y.w < x);
            e += (y.x == x) + (y.y == x) + (y.z == x) + (y.w == x);
        }
        if (c < K && c + e >= K) kv[w][h] = x;   // K-th smallest a of this half's 32-set

        if (l == 0) {
            const float aij = kv[w][0], aji = kv[w][1];
            const float ac = pos ? fminf(aij, aji) : fmaxf(aij, aji);
            const float d = sqrtf(fmaxf(2.0f - 2.0f * ac, 1e-12f));
            const unsigned ud = __float_as_uint(d);   // d >= 0: uint order == float order
            if (pos) atomicMax(&apbuf[i], ud);
            else     atomicMin(&anbuf[i], ud);
        }
    };
    do_pair(acc0, j0);
    do_pair(acc1, j0 + 1);
}

// ---------------- Kernel 3: margin + mean ----------------
__global__ __launch_bounds__(128) void reduce_kernel(const unsigned* __restrict__ apbuf,
                                                     const unsigned* __restrict__ anbuf,
                                                     float* __restrict__ out) {
    const int i = threadIdx.x;   // 0..127
    const float ap = __uint_as_float(apbuf[i]);
    const float an = __uint_as_float(anbuf[i]);
    float li = fmaxf(ap - an + MARGIN, 0.0f);
    #pragma unroll
    for (int off = 32; off; off >>= 1) li += __shfl_xor(li, off);
    __shared__ float ws2[2];
    if ((i & 63) == 0) ws2[i >> 6] = li;
    __syncthreads();
    if (i == 0) out[0] = (ws2[0] + ws2[1]) * (1.0f / (float)NB);
}

extern "C" void kernel_launch(void* const* d_in, const int* in_sizes, int n_in,
                              void* d_out, int out_size, void* d_ws, size_t ws_size,
                              hipStream_t stream) {
    const float* in = (const float*)d_in[0];   // (128,32,256) f32
    const int* tgt = (const int*)d_in[1];      // (128,) i32
    float* out = (float*)d_out;                // scalar

    short* Xhi = (short*)d_ws;                           // 4096*256 bf16 (2 MB)
    unsigned* apbuf = (unsigned*)(Xhi + (size_t)NROW * DF);
    unsigned* anbuf = apbuf + NB;

    norm_kernel<<<NROW, 64, 0, stream>>>(in, Xhi, apbuf, anbuf);
    pair_kernel<<<dim3(16, 128), 256, 0, stream>>>(Xhi, tgt, apbuf, anbuf);
    reduce_kernel<<<1, 128, 0, stream>>>(apbuf, anbuf, out);
}

// Round 5
// 35.048 us; speedup vs baseline: 2.4336x; 2.4336x over previous
//
#include <hip/hip_runtime.h>
#include <hip/hip_bf16.h>

#define NB 128          // tracklets (b)
#define NS 32           // frames per tracklet (s)
#define DF 256          // feature dim
#define NROW (NB*NS)    // 4096
#define KSTEPS (DF/16)  // 16 MFMA k-steps of 16
#define MARGIN 0.3f
#define PANEL (KSTEPS*64)   // bf16x8 slots per tracklet panel

typedef short bf16x8 __attribute__((ext_vector_type(8)));
typedef short bf16x4 __attribute__((ext_vector_type(4)));
typedef float f32x16 __attribute__((ext_vector_type(16)));

__device__ __forceinline__ short f2bf(float x) {      // RTNE float->bf16 bits
    unsigned u = __float_as_uint(x);
    u += 0x7fffu + ((u >> 16) & 1u);
    return (short)(u >> 16);
}

// ---------------- Kernel 1: normalize -> hi-bf16 fragment tiles ----------------
// Tile layout (per tracklet): slot = (trk*KSTEPS + ks)*64 + lane, 8 bf16 per slot.
// lane l covers frame (l&31), k = ks*16 + (l>>5)*8 + e (same mapping for A and B; Gram-symmetric).
__global__ __launch_bounds__(64) void norm_kernel(const float* __restrict__ in,
                                                  short* __restrict__ Xhi) {
    const int row = blockIdx.x;      // 0..4095
    const int lane = threadIdx.x;    // one float4 each
    const float4 v = ((const float4*)(in + (size_t)row * DF))[lane];
    float s = v.x*v.x + v.y*v.y + v.z*v.z + v.w*v.w;
    #pragma unroll
    for (int off = 32; off; off >>= 1) s += __shfl_xor(s, off);
    const float inv = 1.0f / fmaxf(sqrtf(s), 1e-12f);
    const float o[4] = {v.x*inv, v.y*inv, v.z*inv, v.w*inv};

    const int trk = row >> 5, r32 = row & 31;
    const int k4 = lane * 4;
    const int ks = k4 >> 4;
    const int kq = k4 & 15;
    const int tl = ((kq >> 3) << 5) | r32;
    const size_t off8 = ((size_t)(trk * KSTEPS + ks) * 64 + tl) * 8 + (kq & 7);

    bf16x4 hv;
    #pragma unroll
    for (int c = 0; c < 4; c++) hv[c] = f2bf(o[c]);
    *(bf16x4*)(Xhi + off8) = hv;
}

// ---------------- Kernel 2: 1x2 pair-tiles per wave, dual-direction MFMA ----------------
// 8192 waves (2048 blocks); 4 waves/block share the A panel (same i) via L1.
// Both Gram orientations computed by MFMA (operands reuse the same fragments),
// so BOTH frame-min directions are colmax reductions -- no shfl butterfly.
__global__ __launch_bounds__(256) void pair_kernel(const short* __restrict__ Xhi,
                                                   const int* __restrict__ tgt,
                                                   float* __restrict__ val) {
    const int w = threadIdx.x >> 6;
    const int l = threadIdx.x & 63;
    const int h = l >> 5;
    const int t32 = l & 31;
    const int wj = blockIdx.x * 4 + w;   // 0..63
    const int i  = blockIdx.y;           // 0..127
    const int j0 = wj * 2;

    const bf16x8* P  = (const bf16x8*)Xhi;
    const bf16x8* A  = P + (size_t)i  * PANEL + l;
    const bf16x8* B0 = P + (size_t)j0 * PANEL + l;
    const bf16x8* B1 = B0 + PANEL;

    f32x16 acc0, acc1, acc2, acc3;
    #pragma unroll
    for (int r = 0; r < 16; r++) { acc0[r] = 0.0f; acc1[r] = 0.0f; acc2[r] = 0.0f; acc3[r] = 0.0f; }

    #pragma unroll
    for (int ks = 0; ks < KSTEPS; ks++) {
        const bf16x8 a  = A[ks * 64];
        const bf16x8 b0 = B0[ks * 64];
        const bf16x8 b1 = B1[ks * 64];
        acc0 = __builtin_amdgcn_mfma_f32_32x32x16_bf16(a, b0, acc0, 0, 0, 0);  // cols = j0 frames
        acc1 = __builtin_amdgcn_mfma_f32_32x32x16_bf16(a, b1, acc1, 0, 0, 0);  // cols = j1 frames
        acc2 = __builtin_amdgcn_mfma_f32_32x32x16_bf16(b0, a, acc2, 0, 0, 0);  // cols = i frames
        acc3 = __builtin_amdgcn_mfma_f32_32x32x16_bf16(b1, a, acc3, 0, 0, 0);  // cols = i frames
    }

    const int ti = tgt[i];

    __shared__ float buf[4][64];
    __shared__ float kv[4][2];

    // Acc-domain epilogue: d = sqrt(clip(2-2a)) monotone decreasing =>
    // frame-min(d) <-> colmax(a); K-th largest d <-> K-th smallest a;
    // pos-combine max(d) <-> min(a); neg-combine min(d) <-> max(a).
    auto do_pair = [&](const f32x16& accF, const f32x16& accR, int jj) {
        const bool pos = (ti == tgt[jj]);
        const int K = pos ? 3 : 6;

        // colmax over 16 in-lane rows + cross-half swap (both directions)
        float cf = accF[0], cr = accR[0];
        #pragma unroll
        for (int r = 1; r < 16; r++) { cf = fmaxf(cf, accF[r]); cr = fmaxf(cr, accR[r]); }
        cf = fmaxf(cf, __shfl_xor(cf, 32));   // dij candidate, indexed by j-frame t32
        cr = fmaxf(cr, __shfl_xor(cr, 32));   // dji candidate, indexed by i-frame t32

        buf[w][l] = h ? cr : cf;              // [0..31]=ij set, [32..63]=ji set

        const float x = buf[w][l];
        const float* cb = &buf[w][h * 32];
        int c = 0, e = 0;
        #pragma unroll
        for (int q = 0; q < 8; q++) {
            const float4 y = *(const float4*)(cb + 4 * q);
            c += (y.x < x) + (y.y < x) + (y.z < x) + (y.w < x);
            e += (y.x == x) + (y.y == x) + (y.z == x) + (y.w == x);
        }
        if (c < K && c + e >= K) kv[w][h] = x;   // K-th smallest a of this half's 32-set

        if (l == 0) {
            const float aij = kv[w][0], aji = kv[w][1];
            const float ac = pos ? fminf(aij, aji) : fmaxf(aij, aji);
            val[i * NB + jj] = sqrtf(fmaxf(2.0f - 2.0f * ac, 1e-12f));
        }
    };
    do_pair(acc0, acc2, j0);
    do_pair(acc1, acc3, j0 + 1);
}

// ---------------- Kernel 3a: per-anchor ap/an (one wave per anchor) ----------------
__global__ __launch_bounds__(64) void reduce1_kernel(const float* __restrict__ val,
                                                     const int* __restrict__ tgt,
                                                     float* __restrict__ apf,
                                                     float* __restrict__ anf) {
    const int i = blockIdx.x;        // 0..127
    const int l = threadIdx.x;       // 0..63
    const int ti = tgt[i];
    float ap = -1e30f, an = 1e30f;
    #pragma unroll
    for (int q = 0; q < 2; q++) {
        const int j = q * 64 + l;
        const float v = val[i * NB + j];
        if (tgt[j] == ti) ap = fmaxf(ap, v);
        else              an = fminf(an, v);
    }
    #pragma unroll
    for (int off = 32; off; off >>= 1) {
        ap = fmaxf(ap, __shfl_xor(ap, off));
        an = fminf(an, __shfl_xor(an, off));
    }
    if (l == 0) { apf[i] = ap; anf[i] = an; }
}

// ---------------- Kernel 3b: margin + mean ----------------
__global__ __launch_bounds__(128) void reduce2_kernel(const float* __restrict__ apf,
                                                      const float* __restrict__ anf,
                                                      float* __restrict__ out) {
    const int i = threadIdx.x;   // 0..127
    float li = fmaxf(apf[i] - anf[i] + MARGIN, 0.0f);
    #pragma unroll
    for (int off = 32; off; off >>= 1) li += __shfl_xor(li, off);
    __shared__ float ws2[2];
    if ((i & 63) == 0) ws2[i >> 6] = li;
    __syncthreads();
    if (i == 0) out[0] = (ws2[0] + ws2[1]) * (1.0f / (float)NB);
}

extern "C" void kernel_launch(void* const* d_in, const int* in_sizes, int n_in,
                              void* d_out, int out_size, void* d_ws, size_t ws_size,
                              hipStream_t stream) {
    const float* in = (const float*)d_in[0];   // (128,32,256) f32
    const int* tgt = (const int*)d_in[1];      // (128,) i32
    float* out = (float*)d_out;                // scalar

    short* Xhi = (short*)d_ws;                           // 4096*256 bf16 (2 MB)
    float* val = (float*)(Xhi + (size_t)NROW * DF);      // 16384 floats
    float* apf = val + NB * NB;                          // 128
    float* anf = apf + NB;                               // 128

    norm_kernel<<<NROW, 64, 0, stream>>>(in, Xhi);
    pair_kernel<<<dim3(16, 128), 256, 0, stream>>>(Xhi, tgt, val);
    reduce1_kernel<<<NB, 64, 0, stream>>>(val, tgt, apf, anf);
    reduce2_kernel<<<1, 128, 0, stream>>>(apf, anf, out);
}

// Round 6
// 26.183 us; speedup vs baseline: 3.2575x; 1.3386x over previous
//
#include <hip/hip_runtime.h>
#include <hip/hip_bf16.h>

#define NB 128          // tracklets (b)
#define NS 32           // frames per tracklet (s)
#define DF 256          // feature dim
#define NROW (NB*NS)    // 4096
#define KSTEPS (DF/16)  // 16 MFMA k-steps of 16
#define MARGIN 0.3f
#define PANEL (KSTEPS*64)   // bf16x8 slots per tracklet panel
#define NPAIR (NB*(NB+1)/2) // 8256 upper-triangle pairs

typedef short bf16x8 __attribute__((ext_vector_type(8)));
typedef short bf16x4 __attribute__((ext_vector_type(4)));
typedef float f32x16 __attribute__((ext_vector_type(16)));

__device__ __forceinline__ short f2bf(float x) {      // RTNE float->bf16 bits
    unsigned u = __float_as_uint(x);
    u += 0x7fffu + ((u >> 16) & 1u);
    return (short)(u >> 16);
}

// ---------------- Kernel 1: normalize -> hi-bf16 fragment tiles ----------------
// Tile layout (per tracklet): slot = (trk*KSTEPS + ks)*64 + lane, 8 bf16 per slot.
// lane l covers frame (l&31), k = ks*16 + (l>>5)*8 + e (same mapping for A and B; Gram-symmetric).
__global__ __launch_bounds__(64) void norm_kernel(const float* __restrict__ in,
                                                  short* __restrict__ Xhi) {
    const int row = blockIdx.x;      // 0..4095
    const int lane = threadIdx.x;    // one float4 each
    const float4 v = ((const float4*)(in + (size_t)row * DF))[lane];
    float s = v.x*v.x + v.y*v.y + v.z*v.z + v.w*v.w;
    #pragma unroll
    for (int off = 32; off; off >>= 1) s += __shfl_xor(s, off);
    const float inv = 1.0f / fmaxf(sqrtf(s), 1e-12f);
    const float o[4] = {v.x*inv, v.y*inv, v.z*inv, v.w*inv};

    const int trk = row >> 5, r32 = row & 31;
    const int k4 = lane * 4;
    const int ks = k4 >> 4;
    const int kq = k4 & 15;
    const int tl = ((kq >> 3) << 5) | r32;
    const size_t off8 = ((size_t)(trk * KSTEPS + ks) * 64 + tl) * 8 + (kq & 7);

    bf16x4 hv;
    #pragma unroll
    for (int c = 0; c < 4; c++) hv[c] = f2bf(o[c]);
    *(bf16x4*)(Xhi + off8) = hv;
}

// ---------------- Kernel 2: one upper-triangle pair per wave, dual-direction MFMA ----
// val is symmetric in (i,j): the (j,i) block is the transpose, dij/dji swap, and the
// pos/neg combines are max/min of both -> compute i<=j only, write both entries.
__global__ __launch_bounds__(256) void pair_kernel(const short* __restrict__ Xhi,
                                                   const int* __restrict__ tgt,
                                                   float* __restrict__ val) {
    const int w = threadIdx.x >> 6;
    const int l = threadIdx.x & 63;
    const int h = l >> 5;
    const int idx = blockIdx.x * 4 + w;          // 0..8255

    // triangular decode: largest i with base(i) = i*NB - i*(i-1)/2 <= idx
    int i = (int)(128.5f - sqrtf(128.5f * 128.5f - 2.0f * (float)idx));
    while ((i + 1) * NB - ((i + 1) * i) / 2 <= idx) ++i;
    while (i * NB - (i * (i - 1)) / 2 > idx) --i;
    const int j = i + (idx - (i * NB - (i * (i - 1)) / 2));

    const bf16x8* P = (const bf16x8*)Xhi;
    const bf16x8* A = P + (size_t)i * PANEL + l;
    const bf16x8* B = P + (size_t)j * PANEL + l;

    f32x16 accF, accR;
    #pragma unroll
    for (int r = 0; r < 16; r++) { accF[r] = 0.0f; accR[r] = 0.0f; }

    #pragma unroll
    for (int ks = 0; ks < KSTEPS; ks++) {
        const bf16x8 a = A[ks * 64];
        const bf16x8 b = B[ks * 64];
        accF = __builtin_amdgcn_mfma_f32_32x32x16_bf16(a, b, accF, 0, 0, 0);  // cols = j frames
        accR = __builtin_amdgcn_mfma_f32_32x32x16_bf16(b, a, accR, 0, 0, 0);  // cols = i frames
    }

    // Acc-domain epilogue: d = sqrt(clip(2-2a)) monotone decreasing =>
    // frame-min(d) <-> colmax(a); K-th largest d <-> K-th smallest a;
    // pos-combine max(d) <-> min(a); neg-combine min(d) <-> max(a).
    const bool pos = (tgt[i] == tgt[j]);
    const int K = pos ? 3 : 6;

    float cf = accF[0], cr = accR[0];
    #pragma unroll
    for (int r = 1; r < 16; r++) { cf = fmaxf(cf, accF[r]); cr = fmaxf(cr, accR[r]); }
    cf = fmaxf(cf, __shfl_xor(cf, 32));   // dij candidate, indexed by j-frame (l&31)
    cr = fmaxf(cr, __shfl_xor(cr, 32));   // dji candidate, indexed by i-frame (l&31)

    __shared__ float buf[4][64];
    __shared__ float kv[4][2];
    buf[w][l] = h ? cr : cf;              // [0..31]=ij set, [32..63]=ji set

    const float x = buf[w][l];
    const float* cb = &buf[w][h * 32];
    int c = 0, e = 0;
    #pragma unroll
    for (int q = 0; q < 8; q++) {
        const float4 y = *(const float4*)(cb + 4 * q);
        c += (y.x < x) + (y.y < x) + (y.z < x) + (y.w < x);
        e += (y.x == x) + (y.y == x) + (y.z == x) + (y.w == x);
    }
    if (c < K && c + e >= K) kv[w][h] = x;   // K-th smallest a of this half's 32-set

    if (l == 0) {
        const float aij = kv[w][0], aji = kv[w][1];
        const float ac = pos ? fminf(aij, aji) : fmaxf(aij, aji);
        const float d = sqrtf(fmaxf(2.0f - 2.0f * ac, 1e-12f));
        val[i * NB + j] = d;
        val[j * NB + i] = d;
    }
}

// ---------------- Kernel 3: fused per-anchor ap/an + margin + mean ----------------
// 1024 threads: 8 lanes per anchor, each lane covers 16 j's via float4 loads.
__global__ __launch_bounds__(1024) void reduce_kernel(const float* __restrict__ val,
                                                      const int* __restrict__ tgt,
                                                      float* __restrict__ out) {
    __shared__ int   tg[NB];
    __shared__ float ls[NB];
    const int tid = threadIdx.x;
    if (tid < NB) tg[tid] = tgt[tid];
    __syncthreads();

    const int i = tid >> 3;     // anchor 0..127
    const int g = tid & 7;      // lane group 0..7
    const int ti = tg[i];
    float ap = -1e30f, an = 1e30f;
    const float4* vp = (const float4*)(val + i * NB + g * 16);
    #pragma unroll
    for (int q = 0; q < 4; q++) {
        const float4 v = vp[q];
        const int jb = g * 16 + q * 4;
        if (tg[jb + 0] == ti) ap = fmaxf(ap, v.x); else an = fminf(an, v.x);
        if (tg[jb + 1] == ti) ap = fmaxf(ap, v.y); else an = fminf(an, v.y);
        if (tg[jb + 2] == ti) ap = fmaxf(ap, v.z); else an = fminf(an, v.z);
        if (tg[jb + 3] == ti) ap = fmaxf(ap, v.w); else an = fminf(an, v.w);
    }
    #pragma unroll
    for (int off = 1; off < 8; off <<= 1) {
        ap = fmaxf(ap, __shfl_xor(ap, off));
        an = fminf(an, __shfl_xor(an, off));
    }
    if (g == 0) ls[i] = fmaxf(ap - an + MARGIN, 0.0f);
    __syncthreads();

    if (tid < 64) {
        float li = ls[tid] + ls[tid + 64];
        #pragma unroll
        for (int off = 32; off; off >>= 1) li += __shfl_xor(li, off);
        if (tid == 0) out[0] = li * (1.0f / (float)NB);
    }
}

extern "C" void kernel_launch(void* const* d_in, const int* in_sizes, int n_in,
                              void* d_out, int out_size, void* d_ws, size_t ws_size,
                              hipStream_t stream) {
    const float* in = (const float*)d_in[0];   // (128,32,256) f32
    const int* tgt = (const int*)d_in[1];      // (128,) i32
    float* out = (float*)d_out;                // scalar

    short* Xhi = (short*)d_ws;                           // 4096*256 bf16 (2 MB)
    float* val = (float*)(Xhi + (size_t)NROW * DF);      // 16384 floats

    norm_kernel<<<NROW, 64, 0, stream>>>(in, Xhi);
    pair_kernel<<<NPAIR / 4, 256, 0, stream>>>(Xhi, tgt, val);
    reduce_kernel<<<1, 1024, 0, stream>>>(val, tgt, out);
}